// Round 1
// baseline (11530.891 us; speedup 1.0000x reference)
//
#include <hip/hip_runtime.h>
#include <hip/hip_bf16.h>

// Two-layer tanh RNN, B=32 T=512 I=512 H=1024, fp32 in/out, bf16 MFMA compute.
// Layer kernels are persistent: 64 WGs x 128 threads, weights LDS-resident in
// MFMA B-fragment order, one device-scope grid barrier per timestep.

#define B_ 32
#define T_ 512
#define I_ 512
#define H_ 1024

typedef __attribute__((ext_vector_type(8))) short short8;
typedef __attribute__((ext_vector_type(4))) float float4v;

// ---- workspace layout (bytes) ----
// x_bf   : B*T*I bf16            = 16,777,216 B
// h1buf  : (T+1)*B*H bf16        = 33,619,968 B   (slot 0 = zeros = h0)
// hping  : 2*B*H bf16            =    131,072 B   (layer-1 ping/pong)
// bar    : 2 barriers x 256 B
#define OFF_XBF   0ull
#define OFF_H1    16777216ull
#define OFF_HPING 50397184ull
#define OFF_BAR   50528256ull

// Sense-reversing grid barrier: counter at bar[0], generation at bar[16]
// (separate cachelines). Agent-scope acq/rel handles cross-XCD coherence:
// acquire emits buffer_inv (L1+XCD L2), release emits buffer_wbl2.
__device__ __forceinline__ void grid_barrier(unsigned* bar, unsigned nwg) {
  __syncthreads();  // all WG stores drained (s_barrier implies vmcnt wait)
  if (threadIdx.x == 0) {
    unsigned g = __hip_atomic_load(&bar[16], __ATOMIC_RELAXED, __HIP_MEMORY_SCOPE_AGENT);
    unsigned a = __hip_atomic_fetch_add(&bar[0], 1u, __ATOMIC_ACQ_REL, __HIP_MEMORY_SCOPE_AGENT);
    if (a == nwg - 1u) {
      __hip_atomic_store(&bar[0], 0u, __ATOMIC_RELAXED, __HIP_MEMORY_SCOPE_AGENT);
      __hip_atomic_store(&bar[16], g + 1u, __ATOMIC_RELEASE, __HIP_MEMORY_SCOPE_AGENT);
    } else {
      while (__hip_atomic_load(&bar[16], __ATOMIC_ACQUIRE, __HIP_MEMORY_SCOPE_AGENT) == g) {
        __builtin_amdgcn_s_sleep(2);
      }
    }
  }
  __syncthreads();
}

// One RNN layer as a persistent kernel.
//   y[b,c] = tanh( bias[c] + sum_{k<KIN} A0[b,k]*Wih[c,k]
//                          + sum_{k<H}   hprev[b,k]*Whh[c,k] )
// L0: A0 = x_bf[b, t, :]   (xin laid out [B,T,I]);  hprev/out slots in h1buf.
// L1: A0 = h1[t]           (xin = h1buf + B*H, laid out [T,B,H]); ping/pong h.
template<int KIN, bool IS_L1>
__global__ __launch_bounds__(128)
void rnn_layer_kernel(const float* __restrict__ Wih, const float* __restrict__ Whh,
                      const float* __restrict__ bih, const float* __restrict__ bhh,
                      const __hip_bfloat16* __restrict__ xin,
                      __hip_bfloat16* __restrict__ hseq,
                      float* __restrict__ out,
                      unsigned* __restrict__ bar)
{
  constexpr int KTOT = KIN + H_;
  constexpr int NKB0 = KIN / 32;   // k-blocks from input projection
  constexpr int NKB1 = H_ / 32;    // k-blocks from recurrent matrix
  __shared__ unsigned short ldsW[16 * KTOT];  // B-fragment order, 48/64 KB

  const int tid  = threadIdx.x;
  const int lane = tid & 63;
  const int wid  = tid >> 6;              // wave id -> m-tile (rows wid*16..+16)
  const int wg   = blockIdx.x;            // cols wg*16..+16

  // ---- stage weight slice into LDS in MFMA B-fragment order (one time) ----
  // B-frag for 16x16x32 bf16: lane l holds B[k=(l>>4)*8+j][col=l&15].
  // LDS elem index for (kb, lane, j) = (kb*64 + lane)*8 + j.
  for (int idx = tid; idx < 16 * KTOT; idx += 128) {
    int c = idx / KTOT;
    int k = idx - c * KTOT;
    float w = (k < KIN) ? Wih[(size_t)(wg * 16 + c) * KIN + k]
                        : Whh[(size_t)(wg * 16 + c) * H_ + (k - KIN)];
    __hip_bfloat16 hb = __float2bfloat16(w);
    int pos = ((k >> 5) * 64 + ((k >> 3) & 3) * 16 + c) * 8 + (k & 7);
    ldsW[pos] = *reinterpret_cast<unsigned short*>(&hb);
  }

  const int col   = wg * 16 + (lane & 15);        // fixed output col per lane
  const float biasv = bih[col] + bhh[col];        // folded into acc init
  const int arow  = wid * 16 + (lane & 15);       // A-frag row (batch index)
  const int ksub  = ((lane >> 4) & 3) * 8;        // A-frag k sub-offset
  const int lofs  = lane * 8;                     // B-frag LDS offset (elems)
  const int rbase = wid * 16 + (lane >> 4) * 4;   // C-frag row base

  __syncthreads();

  for (int t = 0; t < T_; ++t) {
    const __hip_bfloat16* a0;
    const __hip_bfloat16* a1;
    if constexpr (!IS_L1) {
      a0 = xin  + (size_t)arow * (T_ * I_) + (size_t)t * I_ + ksub;       // x[b,t,:]
      a1 = hseq + (size_t)t * (B_ * H_) + (size_t)arow * H_ + ksub;       // h1 slot t
    } else {
      a0 = xin  + (size_t)t * (B_ * H_) + (size_t)arow * H_ + ksub;       // h1[t]
      a1 = hseq + (size_t)(t & 1) * (B_ * H_) + (size_t)arow * H_ + ksub; // ping
    }

    float4v acc = {biasv, biasv, biasv, biasv};
#pragma unroll 8
    for (int kb = 0; kb < NKB0; ++kb) {
      short8 av = *reinterpret_cast<const short8*>(a0 + kb * 32);
      short8 bv = *reinterpret_cast<const short8*>(ldsW + kb * 512 + lofs);
      acc = __builtin_amdgcn_mfma_f32_16x16x32_bf16(av, bv, acc, 0, 0, 0);
    }
#pragma unroll 8
    for (int kb = 0; kb < NKB1; ++kb) {
      short8 av = *reinterpret_cast<const short8*>(a1 + kb * 32);
      short8 bv = *reinterpret_cast<const short8*>(ldsW + (NKB0 + kb) * 512 + lofs);
      acc = __builtin_amdgcn_mfma_f32_16x16x32_bf16(av, bv, acc, 0, 0, 0);
    }

    __hip_bfloat16* hdst = IS_L1 ? hseq + (size_t)((t + 1) & 1) * (B_ * H_)   // pong
                                 : hseq + (size_t)(t + 1) * (B_ * H_);        // h1 slot t+1
    // C/D layout (m89-verified): col = lane&15, row = (lane>>4)*4 + reg.
#pragma unroll
    for (int r = 0; r < 4; ++r) {
      float hv = tanhf(acc[r]);
      int row = rbase + r;
      hdst[(size_t)row * H_ + col] = __float2bfloat16(hv);
      if constexpr (IS_L1)
        out[(size_t)row * (T_ * H_) + (size_t)t * H_ + col] = hv;
    }
    grid_barrier(bar, gridDim.x);
  }
}

// Convert x to bf16, zero h0 slots and barrier state (ws is poisoned 0xAA
// before every timed call, so everything must be re-initialized here).
__global__ void prep_kernel(const float* __restrict__ x, __hip_bfloat16* __restrict__ x_bf,
                            __hip_bfloat16* __restrict__ h1buf, __hip_bfloat16* __restrict__ hping,
                            unsigned* __restrict__ bar)
{
  int i = blockIdx.x * 256 + threadIdx.x;
  if (i < B_ * T_ * I_) x_bf[i] = __float2bfloat16(x[i]);
  const __hip_bfloat16 z = __float2bfloat16(0.0f);
  if (i < B_ * H_) h1buf[i] = z;
  if (i < 2 * B_ * H_) hping[i] = z;
  if (i < 64) bar[i] = 0u;
}

extern "C" void kernel_launch(void* const* d_in, const int* in_sizes, int n_in,
                              void* d_out, int out_size, void* d_ws, size_t ws_size,
                              hipStream_t stream)
{
  const float* x    = (const float*)d_in[0];
  const float* Wih0 = (const float*)d_in[1];
  const float* Whh0 = (const float*)d_in[2];
  const float* bih0 = (const float*)d_in[3];
  const float* bhh0 = (const float*)d_in[4];
  const float* Wih1 = (const float*)d_in[5];
  const float* Whh1 = (const float*)d_in[6];
  const float* bih1 = (const float*)d_in[7];
  const float* bhh1 = (const float*)d_in[8];
  float* out = (float*)d_out;
  char* ws = (char*)d_ws;

  __hip_bfloat16* x_bf  = (__hip_bfloat16*)(ws + OFF_XBF);
  __hip_bfloat16* h1buf = (__hip_bfloat16*)(ws + OFF_H1);
  __hip_bfloat16* hping = (__hip_bfloat16*)(ws + OFF_HPING);
  unsigned* bar = (unsigned*)(ws + OFF_BAR);

  prep_kernel<<<(B_ * T_ * I_ + 255) / 256, 256, 0, stream>>>(x, x_bf, h1buf, hping, bar);

  // Layer 0: K = 512 (x) + 1024 (h).  64 WGs co-resident (<= 256 CUs) -> the
  // manual grid barrier is deadlock-free.
  rnn_layer_kernel<I_, false><<<64, 128, 0, stream>>>(
      Wih0, Whh0, bih0, bhh0, x_bf, h1buf, nullptr, bar);

  // Layer 1: K = 1024 (h1) + 1024 (h).  Reads h1buf slots 1..512 as input.
  rnn_layer_kernel<H_, true><<<64, 128, 0, stream>>>(
      Wih1, Whh1, bih1, bhh1, h1buf + B_ * H_, hping, out, bar + 32);
}

// Round 2
// 6501.949 us; speedup vs baseline: 1.7735x; 1.7735x over previous
//
#include <hip/hip_runtime.h>
#include <hip/hip_bf16.h>

// Two-layer tanh RNN, B=32 T=512 I=512 H=1024, fp32 in/out, bf16 MFMA compute.
// Single fused persistent kernel: 128 WGs x 128 thr. WGs 0-63 compute layer 0,
// WGs 64-127 compute layer 1, software-pipelined one timestep apart (513 grid
// barriers total). Grid barrier = distributed per-WG release flags + parallel
// acquire polling (no central atomic counter).

#define B_ 32
#define T_ 512
#define I_ 512
#define H_ 1024

typedef __attribute__((ext_vector_type(8))) short short8;
typedef __attribute__((ext_vector_type(4))) float float4v;

// ---- workspace layout (bytes) ----
// x_bf  : B*T*I bf16              = 16,777,216
// h1buf : (T+1)*B*H bf16          = 33,619,968   (slot t = h1 state after t steps)
// hping : 2*B*H bf16              =    131,072   (layer-1 h2 ping/pong)
// flags : 128 * 64 B              =      8,192
#define OFF_XBF   0ull
#define OFF_H1    16777216ull
#define OFF_HPING 50397184ull
#define OFF_FLAGS 50528256ull

__global__ __launch_bounds__(128)
void rnn_fused(const float* __restrict__ Wih0, const float* __restrict__ Whh0,
               const float* __restrict__ bih0, const float* __restrict__ bhh0,
               const float* __restrict__ Wih1, const float* __restrict__ Whh1,
               const float* __restrict__ bih1, const float* __restrict__ bhh1,
               const __hip_bfloat16* __restrict__ x_bf,
               __hip_bfloat16* __restrict__ h1buf,
               __hip_bfloat16* __restrict__ hping,
               float* __restrict__ out,
               unsigned* __restrict__ flags)
{
  __shared__ unsigned short ldsW[16 * 2048];   // 64 KB (L0 role uses 48 KB)
  const int tid  = threadIdx.x;
  const int wgid = blockIdx.x;
  const bool isL1 = (wgid >= 64);
  const int wg   = isL1 ? wgid - 64 : wgid;    // output col tile: cols wg*16..+16
  const int KIN  = isL1 ? H_ : I_;
  const int KTOT = KIN + H_;
  const float* Wih = isL1 ? Wih1 : Wih0;
  const float* Whh = isL1 ? Whh1 : Whh0;

  // ---- stage weight slice into LDS in MFMA B-fragment order (once) ----
  // B-frag (16x16x32 bf16): lane l holds B[k=(l>>4)*8+j][col=l&15], j=0..7.
  for (int idx = tid; idx < 16 * KTOT; idx += 128) {
    int c = idx / KTOT;
    int k = idx - c * KTOT;
    float w = (k < KIN) ? Wih[(size_t)(wg * 16 + c) * KIN + k]
                        : Whh[(size_t)(wg * 16 + c) * H_ + (k - KIN)];
    __hip_bfloat16 hb = __float2bfloat16(w);
    int pos = ((k >> 5) * 64 + ((k >> 3) & 3) * 16 + c) * 8 + (k & 7);
    ldsW[pos] = *reinterpret_cast<unsigned short*>(&hb);
  }

  const int lane  = tid & 63;
  const int wid   = tid >> 6;                    // m-tile: batch rows wid*16..+16
  const int col   = wg * 16 + (lane & 15);
  const float biasv = isL1 ? (bih1[col] + bhh1[col]) : (bih0[col] + bhh0[col]);
  const int arow  = wid * 16 + (lane & 15);      // A-frag row (batch index)
  const int ksub  = ((lane >> 4) & 3) * 8;       // A-frag k sub-offset
  const int lofs  = lane * 8;                    // B-frag LDS elem offset
  const int rbase = wid * 16 + (lane >> 4) * 4;  // C-frag row base

  __syncthreads();

  // Global step s: L0 computes timestep s (writes h1 slot s+1, reads slot s);
  // L1 computes timestep t=s-1 (reads h1 slot s, written at step s-1).
  for (int s = 0; s <= T_; ++s) {
    const bool active = isL1 ? (s >= 1) : (s < T_);
    float4v acc = {biasv, biasv, biasv, biasv};

    // L0's x-projection has no dependence on the pending barrier — issue first.
    if (!isL1 && active) {
      const __hip_bfloat16* a0 = x_bf + (size_t)arow * (T_ * I_) + (size_t)s * I_ + ksub;
#pragma unroll
      for (int kb = 0; kb < 16; ++kb) {
        short8 av = *reinterpret_cast<const short8*>(a0 + kb * 32);
        short8 bv = *reinterpret_cast<const short8*>(ldsW + kb * 512 + lofs);
        acc = __builtin_amdgcn_mfma_f32_16x16x32_bf16(av, bv, acc, 0, 0, 0);
      }
    }

    // ---- wait for barrier s-1: all 128 flags >= s ----
    if (s > 0) {
      if (tid < 64) {
        unsigned* p0 = flags + tid * 16;
        unsigned* p1 = flags + (tid + 64) * 16;
        while (__hip_atomic_load(p0, __ATOMIC_ACQUIRE, __HIP_MEMORY_SCOPE_AGENT) < (unsigned)s)
          __builtin_amdgcn_s_sleep(1);
        while (__hip_atomic_load(p1, __ATOMIC_ACQUIRE, __HIP_MEMORY_SCOPE_AGENT) < (unsigned)s)
          __builtin_amdgcn_s_sleep(1);
      }
      __syncthreads();
    }

    if (active) {
      if (!isL1) {
        // recurrent part: h1 state slot s
        const __hip_bfloat16* a1 = h1buf + (size_t)s * (B_ * H_) + (size_t)arow * H_ + ksub;
#pragma unroll 8
        for (int kb = 0; kb < 32; ++kb) {
          short8 av = *reinterpret_cast<const short8*>(a1 + kb * 32);
          short8 bv = *reinterpret_cast<const short8*>(ldsW + (16 + kb) * 512 + lofs);
          acc = __builtin_amdgcn_mfma_f32_16x16x32_bf16(av, bv, acc, 0, 0, 0);
        }
        __hip_bfloat16* hd = h1buf + (size_t)(s + 1) * (B_ * H_);
#pragma unroll
        for (int r = 0; r < 4; ++r)
          hd[(size_t)(rbase + r) * H_ + col] = __float2bfloat16(tanhf(acc[r]));
      } else {
        const int t = s - 1;
        const __hip_bfloat16* a0 = h1buf + (size_t)s * (B_ * H_) + (size_t)arow * H_ + ksub;
        const __hip_bfloat16* a1 = hping + (size_t)(t & 1) * (B_ * H_) + (size_t)arow * H_ + ksub;
#pragma unroll 8
        for (int kb = 0; kb < 32; ++kb) {
          short8 av = *reinterpret_cast<const short8*>(a0 + kb * 32);
          short8 bv = *reinterpret_cast<const short8*>(ldsW + kb * 512 + lofs);
          acc = __builtin_amdgcn_mfma_f32_16x16x32_bf16(av, bv, acc, 0, 0, 0);
        }
#pragma unroll 8
        for (int kb = 0; kb < 32; ++kb) {
          short8 av = *reinterpret_cast<const short8*>(a1 + kb * 32);
          short8 bv = *reinterpret_cast<const short8*>(ldsW + (32 + kb) * 512 + lofs);
          acc = __builtin_amdgcn_mfma_f32_16x16x32_bf16(av, bv, acc, 0, 0, 0);
        }
        __hip_bfloat16* hd = hping + (size_t)((t + 1) & 1) * (B_ * H_);
#pragma unroll
        for (int r = 0; r < 4; ++r) {
          float hv = tanhf(acc[r]);
          hd[(size_t)(rbase + r) * H_ + col] = __float2bfloat16(hv);
          out[(size_t)(rbase + r) * (T_ * H_) + (size_t)t * H_ + col] = hv;
        }
      }
    }

    // ---- arrive at barrier s: own flag = s+1 (distributed, no contention) ----
    if (s < T_) {
      __syncthreads();  // drain all waves' h stores (compiler emits vmcnt(0) before s_barrier)
      if (tid == 0)
        __hip_atomic_store(flags + wgid * 16, (unsigned)(s + 1),
                           __ATOMIC_RELEASE, __HIP_MEMORY_SCOPE_AGENT);
    }
  }
}

// Re-init every call: ws is poisoned 0xAA before each timed launch.
__global__ void prep_kernel(const float* __restrict__ x, __hip_bfloat16* __restrict__ x_bf,
                            __hip_bfloat16* __restrict__ h1buf, __hip_bfloat16* __restrict__ hping,
                            unsigned* __restrict__ flags)
{
  int i = blockIdx.x * 256 + threadIdx.x;
  if (i < B_ * T_ * I_) x_bf[i] = __float2bfloat16(x[i]);
  const __hip_bfloat16 z = __float2bfloat16(0.0f);
  if (i < B_ * H_) h1buf[i] = z;                 // h1 state slot 0
  if (i < 2 * B_ * H_) hping[i] = z;             // h2 ping + pong
  if (i < 2048) flags[i] = 0u;
}

extern "C" void kernel_launch(void* const* d_in, const int* in_sizes, int n_in,
                              void* d_out, int out_size, void* d_ws, size_t ws_size,
                              hipStream_t stream)
{
  const float* x    = (const float*)d_in[0];
  const float* Wih0 = (const float*)d_in[1];
  const float* Whh0 = (const float*)d_in[2];
  const float* bih0 = (const float*)d_in[3];
  const float* bhh0 = (const float*)d_in[4];
  const float* Wih1 = (const float*)d_in[5];
  const float* Whh1 = (const float*)d_in[6];
  const float* bih1 = (const float*)d_in[7];
  const float* bhh1 = (const float*)d_in[8];
  float* out = (float*)d_out;
  char* ws = (char*)d_ws;

  __hip_bfloat16* x_bf  = (__hip_bfloat16*)(ws + OFF_XBF);
  __hip_bfloat16* h1buf = (__hip_bfloat16*)(ws + OFF_H1);
  __hip_bfloat16* hping = (__hip_bfloat16*)(ws + OFF_HPING);
  unsigned* flags = (unsigned*)(ws + OFF_FLAGS);

  prep_kernel<<<(B_ * T_ * I_ + 255) / 256, 256, 0, stream>>>(x, x_bf, h1buf, hping, flags);

  // 128 WGs, 64 KB LDS each -> trivially co-resident on 256 CUs; the manual
  // grid barrier is deadlock-free.
  rnn_fused<<<128, 128, 0, stream>>>(Wih0, Whh0, bih0, bhh0,
                                     Wih1, Whh1, bih1, bhh1,
                                     x_bf, h1buf, hping, out, flags);
}

// Round 3
// 5247.458 us; speedup vs baseline: 2.1974x; 1.2391x over previous
//
#include <hip/hip_runtime.h>
#include <hip/hip_bf16.h>

// Two-layer tanh RNN, B=32 T=512 I=512 H=1024, fp32 in/out, bf16 MFMA compute.
// Single fused persistent kernel, 128 WGs x 128 thr (WGs 0-63 = layer 0,
// 64-127 = layer 1). NO acquire/release fences in the step loop: cross-WG h
// exchange uses relaxed agent-scope atomics (scope bits route through L3, the
// 8-XCD coherence point) -- this avoids the ~12.5us/step buffer_wbl2 L2-walk
// that round 1/2's release fences paid. Ordering: producer does
// s_waitcnt vmcnt(0) (h stores acked at L3) then relaxed flag store; consumer
// polls flag then loads h (control dep + L3 per-line serialization).
// Layers are decoupled (h1buf keeps all T+1 slots): L0 waits only on L0 flags
// and sprints ahead; L1 waits on L0 (already satisfied) + its own.
// Flags are per (WG, wave): wave w consumes only rows written by wave w of the
// producers -> no __syncthreads in the loop at all.

#define B_ 32
#define T_ 512
#define I_ 512
#define H_ 1024

typedef __attribute__((ext_vector_type(8))) short short8;
typedef __attribute__((ext_vector_type(4))) float float4v;

// ---- workspace layout (bytes) ----
// x_bf  : B*T*I bf16              = 16,777,216
// h1buf : (T+1)*B*H bf16          = 33,619,968   (slot t = h1 state after t steps)
// hping : 2*B*H bf16              =    131,072   (layer-1 h2 ping/pong)
// flags : 256 * 64 B              =     16,384   (per WG per wave, 64B apart)
#define OFF_XBF   0ull
#define OFF_H1    16777216ull
#define OFF_HPING 50397184ull
#define OFF_FLAGS 50528256ull

#define WAIT_VM0() asm volatile("s_waitcnt vmcnt(0)" ::: "memory")
#define CFENCE()   asm volatile("" ::: "memory")

// 16B coherent fragment load (bypasses non-coherent L2s via agent scope bits).
__device__ __forceinline__ short8 ld_cohere16(const __hip_bfloat16* p) {
  unsigned long long* q = (unsigned long long*)p;
  unsigned long long lo = __hip_atomic_load(q,     __ATOMIC_RELAXED, __HIP_MEMORY_SCOPE_AGENT);
  unsigned long long hi = __hip_atomic_load(q + 1, __ATOMIC_RELAXED, __HIP_MEMORY_SCOPE_AGENT);
  union { unsigned long long u[2]; short8 v; } x;
  x.u[0] = lo; x.u[1] = hi;
  return x.v;
}

// Wave-wide wait: lane l polls flag of (producer WG l, wave wid) until >= s.
__device__ __forceinline__ void wait_layer(unsigned* fbase, int lane, int wid, unsigned s) {
  unsigned* p = fbase + (((unsigned)lane << 1) + wid) * 16;
  while (__hip_atomic_load(p, __ATOMIC_RELAXED, __HIP_MEMORY_SCOPE_AGENT) < s)
    __builtin_amdgcn_s_sleep(2);
  CFENCE();
}

__global__ __launch_bounds__(128)
void rnn_fused(const float* __restrict__ Wih0, const float* __restrict__ Whh0,
               const float* __restrict__ bih0, const float* __restrict__ bhh0,
               const float* __restrict__ Wih1, const float* __restrict__ Whh1,
               const float* __restrict__ bih1, const float* __restrict__ bhh1,
               const __hip_bfloat16* __restrict__ x_bf,
               __hip_bfloat16* __restrict__ h1buf,
               __hip_bfloat16* __restrict__ hping,
               float* __restrict__ out,
               unsigned* __restrict__ flags)
{
  __shared__ unsigned short ldsW[16 * 2048];   // 64 KB (L0 role uses 48 KB)
  const int tid  = threadIdx.x;
  const int wgid = blockIdx.x;
  const bool isL1 = (wgid >= 64);
  const int wg   = isL1 ? wgid - 64 : wgid;    // output col tile: cols wg*16..+16
  const int KIN  = isL1 ? H_ : I_;
  const int KTOT = KIN + H_;
  const float* Wih = isL1 ? Wih1 : Wih0;
  const float* Whh = isL1 ? Whh1 : Whh0;

  // ---- stage weight slice into LDS in MFMA B-fragment order (once) ----
  // B-frag (16x16x32 bf16): lane l holds B[k=(l>>4)*8+j][col=l&15], j=0..7.
  for (int idx = tid; idx < 16 * KTOT; idx += 128) {
    int c = idx / KTOT;
    int k = idx - c * KTOT;
    float w = (k < KIN) ? Wih[(size_t)(wg * 16 + c) * KIN + k]
                        : Whh[(size_t)(wg * 16 + c) * H_ + (k - KIN)];
    __hip_bfloat16 hb = __float2bfloat16(w);
    int pos = ((k >> 5) * 64 + ((k >> 3) & 3) * 16 + c) * 8 + (k & 7);
    ldsW[pos] = *reinterpret_cast<unsigned short*>(&hb);
  }

  const int lane  = tid & 63;
  const int wid   = tid >> 6;                    // m-tile: batch rows wid*16..+16
  const int col   = wg * 16 + (lane & 15);
  const float biasv = isL1 ? (bih1[col] + bhh1[col]) : (bih0[col] + bhh0[col]);
  const int arow  = wid * 16 + (lane & 15);      // A-frag row (batch index)
  const int ksub  = ((lane >> 4) & 3) * 8;       // A-frag k sub-offset
  const int lofs  = lane * 8;                    // B-frag LDS elem offset
  const int rbase = wid * 16 + (lane >> 4) * 4;  // C-frag row base
  const int r0    = (lane & 1) ? 2 : 0;          // rows this lane stores (pair-packed)
  const int colp  = col & ~1;                    // even col of the pair

  unsigned* fl0 = flags;                         // L0 flags: (wg*2+wid)*16
  unsigned* fl1 = flags + 128 * 16;              // L1 flags
  unsigned* myflag = (isL1 ? fl1 : fl0) + (((unsigned)wg << 1) + wid) * 16;

  __syncthreads();   // weights staged (only barrier in the kernel)

  if (!isL1) {
    // ================= layer 0 chain =================
    for (int s = 0; s < T_; ++s) {
      float4v acc = {biasv, biasv, biasv, biasv};
      // x-projection: no cross-WG dependence, cached loads, issue before wait
      const __hip_bfloat16* a0 = x_bf + (size_t)arow * (T_ * I_) + (size_t)s * I_ + ksub;
#pragma unroll
      for (int kb = 0; kb < 16; ++kb) {
        short8 av = *reinterpret_cast<const short8*>(a0 + kb * 32);
        short8 bv = *reinterpret_cast<const short8*>(ldsW + kb * 512 + lofs);
        acc = __builtin_amdgcn_mfma_f32_16x16x32_bf16(av, bv, acc, 0, 0, 0);
      }
      if (s > 0) wait_layer(fl0, lane, wid, (unsigned)s);
      const __hip_bfloat16* a1 = h1buf + (size_t)s * (B_ * H_) + (size_t)arow * H_ + ksub;
#pragma unroll 8
      for (int kb = 0; kb < 32; ++kb) {
        short8 av = ld_cohere16(a1 + kb * 32);
        short8 bv = *reinterpret_cast<const short8*>(ldsW + (16 + kb) * 512 + lofs);
        acc = __builtin_amdgcn_mfma_f32_16x16x32_bf16(av, bv, acc, 0, 0, 0);
      }
      // tanh, pack col-pairs via shfl, coherent u32 stores of h1 slot s+1
      __hip_bfloat16* hd = h1buf + (size_t)(s + 1) * (B_ * H_);
      float hv[4];
#pragma unroll
      for (int r = 0; r < 4; ++r) hv[r] = tanhf(acc[r]);
#pragma unroll
      for (int r = 0; r < 4; ++r) {
        float other = __shfl_xor(hv[r], 1, 64);
        float lo = (lane & 1) ? other : hv[r];
        float hi = (lane & 1) ? hv[r] : other;
        __hip_bfloat16 l16 = __float2bfloat16(lo), h16 = __float2bfloat16(hi);
        unsigned pk = (unsigned)*(unsigned short*)&l16 | ((unsigned)*(unsigned short*)&h16 << 16);
        if (r == r0 || r == r0 + 1) {
          unsigned* dst = (unsigned*)(hd + (size_t)(rbase + r) * H_ + colp);
          __hip_atomic_store(dst, pk, __ATOMIC_RELAXED, __HIP_MEMORY_SCOPE_AGENT);
        }
      }
      WAIT_VM0();                                  // h acked at L3
      if (lane == 0)
        __hip_atomic_store(myflag, (unsigned)(s + 1), __ATOMIC_RELAXED, __HIP_MEMORY_SCOPE_AGENT);
    }
  } else {
    // ================= layer 1 chain =================
    for (int t = 0; t < T_; ++t) {
      float4v acc = {biasv, biasv, biasv, biasv};
      // input part: h1 output of timestep t = slot t+1 (ready when fl0 >= t+1)
      wait_layer(fl0, lane, wid, (unsigned)(t + 1));
      const __hip_bfloat16* a0 = h1buf + (size_t)(t + 1) * (B_ * H_) + (size_t)arow * H_ + ksub;
#pragma unroll 8
      for (int kb = 0; kb < 32; ++kb) {
        short8 av = ld_cohere16(a0 + kb * 32);
        short8 bv = *reinterpret_cast<const short8*>(ldsW + kb * 512 + lofs);
        acc = __builtin_amdgcn_mfma_f32_16x16x32_bf16(av, bv, acc, 0, 0, 0);
      }
      if (t > 0) wait_layer(fl1, lane, wid, (unsigned)t);
      const __hip_bfloat16* a1 = hping + (size_t)(t & 1) * (B_ * H_) + (size_t)arow * H_ + ksub;
#pragma unroll 8
      for (int kb = 0; kb < 32; ++kb) {
        short8 av = ld_cohere16(a1 + kb * 32);
        short8 bv = *reinterpret_cast<const short8*>(ldsW + (32 + kb) * 512 + lofs);
        acc = __builtin_amdgcn_mfma_f32_16x16x32_bf16(av, bv, acc, 0, 0, 0);
      }
      __hip_bfloat16* hd = hping + (size_t)((t + 1) & 1) * (B_ * H_);
      float hv[4];
#pragma unroll
      for (int r = 0; r < 4; ++r) hv[r] = tanhf(acc[r]);
#pragma unroll
      for (int r = 0; r < 4; ++r) {
        float other = __shfl_xor(hv[r], 1, 64);
        float lo = (lane & 1) ? other : hv[r];
        float hi = (lane & 1) ? hv[r] : other;
        if (r == r0 || r == r0 + 1) {
          __hip_bfloat16 l16 = __float2bfloat16(lo), h16 = __float2bfloat16(hi);
          unsigned pk = (unsigned)*(unsigned short*)&l16 | ((unsigned)*(unsigned short*)&h16 << 16);
          unsigned* dst = (unsigned*)(hd + (size_t)(rbase + r) * H_ + colp);
          __hip_atomic_store(dst, pk, __ATOMIC_RELAXED, __HIP_MEMORY_SCOPE_AGENT);
          // fp32 output, normal cached store (flushed at dispatch end)
          float2 f2; f2.x = lo; f2.y = hi;
          *(float2*)(out + (size_t)(rbase + r) * (T_ * H_) + (size_t)t * H_ + colp) = f2;
        }
      }
      WAIT_VM0();
      if (lane == 0)
        __hip_atomic_store(myflag, (unsigned)(t + 1), __ATOMIC_RELAXED, __HIP_MEMORY_SCOPE_AGENT);
    }
  }
}

// Re-init every call (ws poisoned 0xAA before each timed launch):
// x -> bf16 (vectorized), zero h1 slot 0 / hping / flags via coherent stores.
__global__ void prep_kernel(const float* __restrict__ x, unsigned long long* __restrict__ x64,
                            unsigned* __restrict__ h1z, unsigned* __restrict__ hpz,
                            unsigned* __restrict__ flags)
{
  int i = blockIdx.x * 256 + threadIdx.x;
  if (i < (B_ * T_ * I_) / 4) {
    const float4* x4 = (const float4*)x;
    float4 v = x4[i];
    __hip_bfloat16 b0 = __float2bfloat16(v.x), b1 = __float2bfloat16(v.y);
    __hip_bfloat16 b2 = __float2bfloat16(v.z), b3 = __float2bfloat16(v.w);
    unsigned long long r = (unsigned long long)*(unsigned short*)&b0
                         | ((unsigned long long)*(unsigned short*)&b1 << 16)
                         | ((unsigned long long)*(unsigned short*)&b2 << 32)
                         | ((unsigned long long)*(unsigned short*)&b3 << 48);
    x64[i] = r;
  }
  if (i < 16384) __hip_atomic_store(h1z + i, 0u, __ATOMIC_RELAXED, __HIP_MEMORY_SCOPE_AGENT);
  if (i < 32768) __hip_atomic_store(hpz + i, 0u, __ATOMIC_RELAXED, __HIP_MEMORY_SCOPE_AGENT);
  if (i < 4096)  __hip_atomic_store(flags + i, 0u, __ATOMIC_RELAXED, __HIP_MEMORY_SCOPE_AGENT);
}

extern "C" void kernel_launch(void* const* d_in, const int* in_sizes, int n_in,
                              void* d_out, int out_size, void* d_ws, size_t ws_size,
                              hipStream_t stream)
{
  const float* x    = (const float*)d_in[0];
  const float* Wih0 = (const float*)d_in[1];
  const float* Whh0 = (const float*)d_in[2];
  const float* bih0 = (const float*)d_in[3];
  const float* bhh0 = (const float*)d_in[4];
  const float* Wih1 = (const float*)d_in[5];
  const float* Whh1 = (const float*)d_in[6];
  const float* bih1 = (const float*)d_in[7];
  const float* bhh1 = (const float*)d_in[8];
  float* out = (float*)d_out;
  char* ws = (char*)d_ws;

  __hip_bfloat16* x_bf  = (__hip_bfloat16*)(ws + OFF_XBF);
  __hip_bfloat16* h1buf = (__hip_bfloat16*)(ws + OFF_H1);
  __hip_bfloat16* hping = (__hip_bfloat16*)(ws + OFF_HPING);
  unsigned* flags = (unsigned*)(ws + OFF_FLAGS);

  prep_kernel<<<(B_ * T_ * I_ / 4 + 255) / 256, 256, 0, stream>>>(
      x, (unsigned long long*)x_bf, (unsigned*)h1buf, (unsigned*)hping, flags);

  // 128 WGs, 64 KB LDS -> 2 WGs/CU cap, trivially co-resident on 256 CUs;
  // flag waits are deadlock-free (L0 depends only on L0; L1 on L0+L1).
  rnn_fused<<<128, 128, 0, stream>>>(Wih0, Whh0, bih0, bhh0,
                                     Wih1, Whh1, bih1, bhh1,
                                     x_bf, h1buf, hping, out, flags);
}

// Round 4
// 2828.734 us; speedup vs baseline: 4.0763x; 1.8551x over previous
//
#include <hip/hip_runtime.h>
#include <hip/hip_bf16.h>

// Two-layer tanh RNN, B=32 T=512 I=512 H=1024, fp32 in/out, bf16 MFMA compute.
// Fused persistent kernel, 128 WGs x 128 thr (WGs 0-63 = L0, 64-127 = L1).
// Round-4 change: cross-WG h loads are inline-asm global_load_dwordx4 sc1
// (agent-scope, L2-bypass) issued in BATCHES with staged s_waitcnt vmcnt(N),
// replacing round-3's per-fragment __hip_atomic_load which codegen'd as
// load->vmcnt(0)->mfma serialization (~900 cyc x 64 frags ~= the whole 10us
// step). Flags stay relaxed agent atomics; producer orders h-stores before
// flag with s_waitcnt vmcnt(0).

#define B_ 32
#define T_ 512
#define I_ 512
#define H_ 1024

typedef __attribute__((ext_vector_type(8))) short short8;
typedef __attribute__((ext_vector_type(4))) float float4v;

// ---- workspace layout (bytes) ----
#define OFF_XBF   0ull            // x_bf : B*T*I bf16 = 16,777,216
#define OFF_H1    16777216ull     // h1buf: (T+1)*B*H bf16 = 33,619,968
#define OFF_HPING 50397184ull     // hping: 2*B*H bf16 = 131,072
#define OFF_FLAGS 50528256ull     // flags: 256 * 64 B

#define WAIT_VM0() asm volatile("s_waitcnt vmcnt(0)" ::: "memory")
#define CFENCE()   asm volatile("" ::: "memory")

// Issue one 16B L2-bypassing load (agent-coherent). No implicit wait.
#define LDF(f, base, O) \
  asm volatile("global_load_dwordx4 %0, %1, off offset:%2 sc1" \
               : "=v"(f) : "v"(base), "n"(O) : "memory")

// Issue 8 fragments from base + OB.. (+448). 64 B per fragment (32 bf16).
#define LD8(F, S, BASE, OB) \
  LDF(F[S+0], BASE, OB+0);   LDF(F[S+1], BASE, OB+64); \
  LDF(F[S+2], BASE, OB+128); LDF(F[S+3], BASE, OB+192); \
  LDF(F[S+4], BASE, OB+256); LDF(F[S+5], BASE, OB+320); \
  LDF(F[S+6], BASE, OB+384); LDF(F[S+7], BASE, OB+448)

// Wait until <=N vector-mem ops outstanding; ties the 8 fragments through the
// asm so the scheduler cannot hoist their consuming MFMAs above the wait.
// (vmcnt retires oldest-first, so extra older in-flight ops only over-wait.)
#define VMW8(N, F, S) \
  asm volatile("s_waitcnt vmcnt(" #N ")" \
               : "+v"(F[S+0]), "+v"(F[S+1]), "+v"(F[S+2]), "+v"(F[S+3]), \
                 "+v"(F[S+4]), "+v"(F[S+5]), "+v"(F[S+6]), "+v"(F[S+7]))

#define MFMA_B(acc, f, kb) \
  acc = __builtin_amdgcn_mfma_f32_16x16x32_bf16( \
      f, *reinterpret_cast<const short8*>(ldsW + (kb) * 512 + lofs), acc, 0, 0, 0)

// 8 MFMAs for fragments F[S..S+7] against k-blocks KB..KB+7, alternating two
// accumulator chains (halves the dependent-MFMA latency chain).
#define MF8(F, S, KB) \
  MFMA_B(accA, F[S+0], KB+0); MFMA_B(accB, F[S+1], KB+1); \
  MFMA_B(accA, F[S+2], KB+2); MFMA_B(accB, F[S+3], KB+3); \
  MFMA_B(accA, F[S+4], KB+4); MFMA_B(accB, F[S+5], KB+5); \
  MFMA_B(accA, F[S+6], KB+6); MFMA_B(accB, F[S+7], KB+7)

// tanh(x) = 1 - 2/(exp2(2*log2e*x)+1); exact at saturation, ~1ulp rcp error
// (absorbed by bf16 storage). Much shorter dependency chain than libm tanhf.
__device__ __forceinline__ float fast_tanh(float x) {
  float z = fminf(2.885390081777927f * x, 60.0f);
  float e = __builtin_amdgcn_exp2f(z);
  return 1.0f - 2.0f * __builtin_amdgcn_rcpf(e + 1.0f);
}

// Lane l polls flag of (producer WG l, wave wid) until >= s.
__device__ __forceinline__ void wait_layer(unsigned* fbase, int lane, int wid, unsigned s) {
  unsigned* p = fbase + (((unsigned)lane << 1) + wid) * 16;
  while (__hip_atomic_load(p, __ATOMIC_RELAXED, __HIP_MEMORY_SCOPE_AGENT) < s)
    __builtin_amdgcn_s_sleep(1);
  CFENCE();
}

__global__ __launch_bounds__(128)
void rnn_fused(const float* __restrict__ Wih0, const float* __restrict__ Whh0,
               const float* __restrict__ bih0, const float* __restrict__ bhh0,
               const float* __restrict__ Wih1, const float* __restrict__ Whh1,
               const float* __restrict__ bih1, const float* __restrict__ bhh1,
               const __hip_bfloat16* __restrict__ x_bf,
               __hip_bfloat16* __restrict__ h1buf,
               __hip_bfloat16* __restrict__ hping,
               float* __restrict__ out,
               unsigned* __restrict__ flags)
{
  __shared__ unsigned short ldsW[16 * 2048];   // 64 KB (L0 uses 48 KB)
  const int tid  = threadIdx.x;
  const int wgid = blockIdx.x;
  const bool isL1 = (wgid >= 64);
  const int wg   = isL1 ? wgid - 64 : wgid;    // output cols wg*16..+16
  const int KIN  = isL1 ? H_ : I_;
  const int KTOT = KIN + H_;
  const float* Wih = isL1 ? Wih1 : Wih0;
  const float* Whh = isL1 ? Whh1 : Whh0;

  // Stage weight slice into LDS in MFMA B-fragment order (once).
  for (int idx = tid; idx < 16 * KTOT; idx += 128) {
    int c = idx / KTOT;
    int k = idx - c * KTOT;
    float w = (k < KIN) ? Wih[(size_t)(wg * 16 + c) * KIN + k]
                        : Whh[(size_t)(wg * 16 + c) * H_ + (k - KIN)];
    __hip_bfloat16 hb = __float2bfloat16(w);
    int pos = ((k >> 5) * 64 + ((k >> 3) & 3) * 16 + c) * 8 + (k & 7);
    ldsW[pos] = *reinterpret_cast<unsigned short*>(&hb);
  }

  const int lane  = tid & 63;
  const int wid   = tid >> 6;                    // m-tile: batch rows wid*16..+16
  const int col   = wg * 16 + (lane & 15);
  const float biasv = isL1 ? (bih1[col] + bhh1[col]) : (bih0[col] + bhh0[col]);
  const int arow  = wid * 16 + (lane & 15);      // A-frag row (batch index)
  const int ksub  = ((lane >> 4) & 3) * 8;       // A-frag k sub-offset
  const int lofs  = lane * 8;                    // B-frag LDS elem offset
  const int rbase = wid * 16 + (lane >> 4) * 4;  // C-frag row base
  const int r0    = (lane & 1) ? 2 : 0;          // rows this lane stores
  const int colp  = col & ~1;

  unsigned* fl0 = flags;
  unsigned* fl1 = flags + 128 * 16;
  unsigned* myflag = (isL1 ? fl1 : fl0) + (((unsigned)wg << 1) + wid) * 16;

  __syncthreads();   // weights staged (only __syncthreads in the kernel)

  if (!isL1) {
    // ================= layer 0 =================
    for (int s = 0; s < T_; ++s) {
      float4v accA = {biasv, biasv, biasv, biasv};
      float4v accB = {0.f, 0.f, 0.f, 0.f};
      // x-projection: cached loads, independent of the flag wait.
      const __hip_bfloat16* a0 = x_bf + (size_t)arow * (T_ * I_) + (size_t)s * I_ + ksub;
#pragma unroll
      for (int kb = 0; kb < 16; ++kb) {
        short8 av = *reinterpret_cast<const short8*>(a0 + kb * 32);
        MFMA_B(accA, av, kb);
      }
      if (s > 0) wait_layer(fl0, lane, wid, (unsigned)s);
      const __hip_bfloat16* a1 = h1buf + (size_t)s * (B_ * H_) + (size_t)arow * H_ + ksub;
      short8 g[32];
      LD8(g, 0, a1, 0);  LD8(g, 8, a1, 512);  LD8(g, 16, a1, 1024);  LD8(g, 24, a1, 1536);
      VMW8(24, g, 0);   MF8(g, 0, 16);
      VMW8(16, g, 8);   MF8(g, 8, 24);
      VMW8(8,  g, 16);  MF8(g, 16, 32);
      VMW8(0,  g, 24);  MF8(g, 24, 40);

      __hip_bfloat16* hd = h1buf + (size_t)(s + 1) * (B_ * H_);
      float hv[4];
#pragma unroll
      for (int r = 0; r < 4; ++r) hv[r] = fast_tanh(accA[r] + accB[r]);
#pragma unroll
      for (int r = 0; r < 4; ++r) {
        float other = __shfl_xor(hv[r], 1, 64);
        float lo = (lane & 1) ? other : hv[r];
        float hi = (lane & 1) ? hv[r] : other;
        if (r == r0 || r == r0 + 1) {
          __hip_bfloat16 l16 = __float2bfloat16(lo), h16 = __float2bfloat16(hi);
          unsigned pk = (unsigned)*(unsigned short*)&l16 | ((unsigned)*(unsigned short*)&h16 << 16);
          unsigned* dst = (unsigned*)(hd + (size_t)(rbase + r) * H_ + colp);
          __hip_atomic_store(dst, pk, __ATOMIC_RELAXED, __HIP_MEMORY_SCOPE_AGENT);
        }
      }
      WAIT_VM0();                                  // h acked at L3 (coherence point)
      if (lane == 0)
        __hip_atomic_store(myflag, (unsigned)(s + 1), __ATOMIC_RELAXED, __HIP_MEMORY_SCOPE_AGENT);
    }
  } else {
    // ================= layer 1 =================
    for (int t = 0; t < T_; ++t) {
      float4v accA = {biasv, biasv, biasv, biasv};
      float4v accB = {0.f, 0.f, 0.f, 0.f};
      wait_layer(fl0, lane, wid, (unsigned)(t + 1));   // L0 runs ahead: usually free
      if (t > 0) wait_layer(fl1, lane, wid, (unsigned)t);
      const __hip_bfloat16* aA = h1buf + (size_t)(t + 1) * (B_ * H_) + (size_t)arow * H_ + ksub;
      const __hip_bfloat16* aB = hping + (size_t)(t & 1) * (B_ * H_) + (size_t)arow * H_ + ksub;
      short8 g[32], h[32];
      LD8(g, 0, aA, 0);  LD8(g, 8, aA, 512);  LD8(g, 16, aA, 1024);  LD8(g, 24, aA, 1536);
      // Second half's loads issue under the first half's MFMAs (<=32 in flight).
      VMW8(24, g, 0);   MF8(g, 0, 0);    LD8(h, 0, aB, 0);
      VMW8(24, g, 8);   MF8(g, 8, 8);    LD8(h, 8, aB, 512);
      VMW8(24, g, 16);  MF8(g, 16, 16);  LD8(h, 16, aB, 1024);
      VMW8(24, g, 24);  MF8(g, 24, 24);  LD8(h, 24, aB, 1536);
      VMW8(24, h, 0);   MF8(h, 0, 32);
      VMW8(16, h, 8);   MF8(h, 8, 40);
      VMW8(8,  h, 16);  MF8(h, 16, 48);
      VMW8(0,  h, 24);  MF8(h, 24, 56);

      __hip_bfloat16* hd = hping + (size_t)((t + 1) & 1) * (B_ * H_);
      float hv[4];
#pragma unroll
      for (int r = 0; r < 4; ++r) hv[r] = fast_tanh(accA[r] + accB[r]);
      float lov[4], hiv[4];
#pragma unroll
      for (int r = 0; r < 4; ++r) {
        float other = __shfl_xor(hv[r], 1, 64);
        lov[r] = (lane & 1) ? other : hv[r];
        hiv[r] = (lane & 1) ? hv[r] : other;
        if (r == r0 || r == r0 + 1) {
          __hip_bfloat16 l16 = __float2bfloat16(lov[r]), h16 = __float2bfloat16(hiv[r]);
          unsigned pk = (unsigned)*(unsigned short*)&l16 | ((unsigned)*(unsigned short*)&h16 << 16);
          unsigned* dst = (unsigned*)(hd + (size_t)(rbase + r) * H_ + colp);
          __hip_atomic_store(dst, pk, __ATOMIC_RELAXED, __HIP_MEMORY_SCOPE_AGENT);
        }
      }
      WAIT_VM0();                                  // only the 2 h stores outstanding here
      if (lane == 0)
        __hip_atomic_store(myflag, (unsigned)(t + 1), __ATOMIC_RELAXED, __HIP_MEMORY_SCOPE_AGENT);
      // fp32 output stores AFTER the flag: off the critical path (drained by
      // next step's WAIT_VM0 / end-of-kernel flush).
#pragma unroll
      for (int r = 0; r < 4; ++r) {
        if (r == r0 || r == r0 + 1) {
          float2 f2; f2.x = lov[r]; f2.y = hiv[r];
          *(float2*)(out + (size_t)(rbase + r) * (T_ * H_) + (size_t)t * H_ + colp) = f2;
        }
      }
    }
  }
}

// Re-init every call (ws poisoned 0xAA before each timed launch).
__global__ void prep_kernel(const float* __restrict__ x, unsigned long long* __restrict__ x64,
                            unsigned* __restrict__ h1z, unsigned* __restrict__ hpz,
                            unsigned* __restrict__ flags)
{
  int i = blockIdx.x * 256 + threadIdx.x;
  if (i < (B_ * T_ * I_) / 4) {
    const float4* x4 = (const float4*)x;
    float4 v = x4[i];
    __hip_bfloat16 b0 = __float2bfloat16(v.x), b1 = __float2bfloat16(v.y);
    __hip_bfloat16 b2 = __float2bfloat16(v.z), b3 = __float2bfloat16(v.w);
    unsigned long long r = (unsigned long long)*(unsigned short*)&b0
                         | ((unsigned long long)*(unsigned short*)&b1 << 16)
                         | ((unsigned long long)*(unsigned short*)&b2 << 32)
                         | ((unsigned long long)*(unsigned short*)&b3 << 48);
    x64[i] = r;
  }
  if (i < 16384) __hip_atomic_store(h1z + i, 0u, __ATOMIC_RELAXED, __HIP_MEMORY_SCOPE_AGENT);
  if (i < 32768) __hip_atomic_store(hpz + i, 0u, __ATOMIC_RELAXED, __HIP_MEMORY_SCOPE_AGENT);
  if (i < 4096)  __hip_atomic_store(flags + i, 0u, __ATOMIC_RELAXED, __HIP_MEMORY_SCOPE_AGENT);
}

extern "C" void kernel_launch(void* const* d_in, const int* in_sizes, int n_in,
                              void* d_out, int out_size, void* d_ws, size_t ws_size,
                              hipStream_t stream)
{
  const float* x    = (const float*)d_in[0];
  const float* Wih0 = (const float*)d_in[1];
  const float* Whh0 = (const float*)d_in[2];
  const float* bih0 = (const float*)d_in[3];
  const float* bhh0 = (const float*)d_in[4];
  const float* Wih1 = (const float*)d_in[5];
  const float* Whh1 = (const float*)d_in[6];
  const float* bih1 = (const float*)d_in[7];
  const float* bhh1 = (const float*)d_in[8];
  float* out = (float*)d_out;
  char* ws = (char*)d_ws;

  __hip_bfloat16* x_bf  = (__hip_bfloat16*)(ws + OFF_XBF);
  __hip_bfloat16* h1buf = (__hip_bfloat16*)(ws + OFF_H1);
  __hip_bfloat16* hping = (__hip_bfloat16*)(ws + OFF_HPING);
  unsigned* flags = (unsigned*)(ws + OFF_FLAGS);

  prep_kernel<<<(B_ * T_ * I_ / 4 + 255) / 256, 256, 0, stream>>>(
      x, (unsigned long long*)x_bf, (unsigned*)h1buf, (unsigned*)hping, flags);

  rnn_fused<<<128, 128, 0, stream>>>(Wih0, Whh0, bih0, bhh0,
                                     Wih1, Whh1, bih1, bhh1,
                                     x_bf, h1buf, hping, out, flags);
}